// Round 5
// baseline (1128.916 us; speedup 1.0000x reference)
//
#include <hip/hip_runtime.h>
#include <hip/hip_bf16.h>

#define HH 64      // hidden
#define TT 256     // seq len
#define NB 1024    // batch
#define GG 256     // 4*H gates
#define DD0 5      // layer-0 input dim
#define DD1 128    // layer-1 input dim (2*H)

typedef __attribute__((ext_vector_type(8))) short bf16x8;  // 8 bf16 = 4 VGPR
typedef __attribute__((ext_vector_type(4))) float f32x4;   // MFMA C/D frag

#define MFMA16(a, b, c) __builtin_amdgcn_mfma_f32_16x16x32_bf16((a), (b), (c), 0, 0, 0)

__device__ __forceinline__ float sigf(float x) { return 1.0f / (1.0f + __expf(-x)); }
__device__ __forceinline__ float tanh_fast(float x) { return 2.0f / (1.0f + __expf(-2.0f * x)) - 1.0f; }

__device__ __forceinline__ float bf2f(short s) {
    unsigned int u = ((unsigned int)(unsigned short)s) << 16;
    return __builtin_bit_cast(float, u);
}
__device__ __forceinline__ short f2bf_rne(float x) {
    unsigned int u = __builtin_bit_cast(unsigned int, x);
    u += 0x7fffu + ((u >> 16) & 1u);  // round-to-nearest-even
    return (short)(u >> 16);
}

// Lane-linear A-fragment store for h (conflict-free ds_read_b128):
// reader lane l, seg s reads shorts [s*512 + l*8, +8).
// h_hi[row][u] lives at: seg = u>>5, lane' = ((u>>3)&3)*16 + row, elem = u&7.
__device__ __forceinline__ int hsf_waddr(int u, int row) {
    return ((u >> 5) * 512) + (((u >> 3) & 3) * 128) + row * 8 + (u & 7);  // lo: +1024
}

// ---------------------------------------------------------------------------
// Layer 0, MFMA recurrence. 1024 blocks = 512 row-pairs x 2 dirs -> 4/CU.
// 256 threads = 4 waves; wave w owns n-tile quad {w,w+4,w+8,w+12} so lane
// (rg==0, col) holds i,f,g,o of unit u = 16w+col for rows 0..1 in its own
// accumulator regs. h = split-bf16 (hi+lo) 3-combo MFMA; x-part (D=5) exact
// fp32 VALU. hsf double-buffered, one barrier/step.
// ---------------------------------------------------------------------------
__launch_bounds__(256, 4)
__global__ void lstm_l0(const float* __restrict__ x,
                        const float* __restrict__ w_ih_f, const float* __restrict__ w_hh_f,
                        const float* __restrict__ b_ih_f, const float* __restrict__ b_hh_f,
                        const float* __restrict__ w_ih_r, const float* __restrict__ w_hh_r,
                        const float* __restrict__ b_ih_r, const float* __restrict__ b_hh_r,
                        short* __restrict__ out0) {
    const int tid  = threadIdx.x;
    const int w    = tid >> 6;
    const int l    = tid & 63;
    const int col  = l & 15;
    const int rg   = l >> 4;
    const int dir  = blockIdx.x & 1;
    const int row0 = (blockIdx.x >> 1) * 2;
    const int u    = w * 16 + col;

    const float* w_ih = dir ? w_ih_r : w_ih_f;
    const float* w_hh = dir ? w_hh_r : w_hh_f;
    const float* b_ih = dir ? b_ih_r : b_ih_f;
    const float* b_hh = dir ? b_hh_r : b_hh_f;

    __shared__ __align__(16) float xs[2 * TT * DD0];  // 10 KB
    __shared__ __align__(16) short hsf[2][2048];      // 8 KB: [buf][seg*512 + lane*8 + e]

    {   // stage x: 2 rows x 1280 contiguous floats
        const float4* src = (const float4*)(x + (size_t)row0 * TT * DD0);
        for (int i = tid; i < 2 * TT * DD0 / 4; i += 256) ((float4*)xs)[i] = src[i];
    }
    for (int i = tid; i < 2 * 2048; i += 256) ((short*)hsf)[i] = 0;

    bf16x8 whh_hi[4][2], whh_lo[4][2];
#pragma unroll
    for (int q = 0; q < 4; ++q) {
        const int gate = (w + 4 * q) * 16 + col;
#pragma unroll
        for (int ks = 0; ks < 2; ++ks) {
            const float* src = w_hh + gate * HH + ks * 32 + 8 * rg;
#pragma unroll
            for (int e = 0; e < 8; ++e) {
                float v = src[e];
                short h16 = f2bf_rne(v);
                whh_hi[q][ks][e] = h16;
                whh_lo[q][ks][e] = f2bf_rne(v - bf2f(h16));
            }
        }
    }
    float wxi[4][DD0], bb[4];
#pragma unroll
    for (int gi = 0; gi < 4; ++gi) {
        const int gate = u + 64 * gi;
#pragma unroll
        for (int d = 0; d < DD0; ++d) wxi[gi][d] = w_ih[gate * DD0 + d];
        bb[gi] = b_ih[gate] + b_hh[gate];
    }

    float cc[2] = {0.f, 0.f};
    __syncthreads();

    for (int t = 0; t < TT; ++t) {
        const int tt  = dir ? (TT - 1 - t) : t;
        const int cur = t & 1, nxt = cur ^ 1;
        const short* hb = &hsf[cur][0];
        bf16x8 ah0 = *(const bf16x8*)&hb[0 * 512 + l * 8];  // h_hi k 0..31
        bf16x8 ah1 = *(const bf16x8*)&hb[1 * 512 + l * 8];  // h_hi k 32..63
        bf16x8 ah2 = *(const bf16x8*)&hb[2 * 512 + l * 8];  // h_lo k 0..31
        bf16x8 ah3 = *(const bf16x8*)&hb[3 * 512 + l * 8];  // h_lo k 32..63
        f32x4 acc[4];
#pragma unroll
        for (int q = 0; q < 4; ++q) {
            f32x4 a = {0.f, 0.f, 0.f, 0.f};
            a = MFMA16(ah0, whh_hi[q][0], a);
            a = MFMA16(ah1, whh_hi[q][1], a);
            a = MFMA16(ah2, whh_hi[q][0], a);
            a = MFMA16(ah3, whh_hi[q][1], a);
            a = MFMA16(ah0, whh_lo[q][0], a);
            a = MFMA16(ah1, whh_lo[q][1], a);
            acc[q] = a;
        }
        if (rg == 0) {
#pragma unroll
            for (int r = 0; r < 2; ++r) {
                const float* xr = &xs[r * TT * DD0 + tt * DD0];
                const float xv0 = xr[0], xv1 = xr[1], xv2 = xr[2], xv3 = xr[3], xv4 = xr[4];
                float g4[4];
#pragma unroll
                for (int gi = 0; gi < 4; ++gi)
                    g4[gi] = acc[gi][r] + bb[gi]
                           + wxi[gi][0] * xv0 + wxi[gi][1] * xv1 + wxi[gi][2] * xv2
                           + wxi[gi][3] * xv3 + wxi[gi][4] * xv4;
                const float cn = sigf(g4[1]) * cc[r] + sigf(g4[0]) * tanh_fast(g4[2]);
                const float hn = sigf(g4[3]) * tanh_fast(cn);
                cc[r] = cn;
                const short hi16 = f2bf_rne(hn);
                const short lo16 = f2bf_rne(hn - bf2f(hi16));
                const int wa = hsf_waddr(u, r);
                hsf[nxt][wa]        = hi16;
                hsf[nxt][wa + 1024] = lo16;
                const size_t ob = ((size_t)(row0 + r) * TT + tt) * GG;
                out0[ob + dir * 64 + u]       = hi16;
                out0[ob + 128 + dir * 64 + u] = lo16;
            }
        }
        __syncthreads();
    }
}

// ---------------------------------------------------------------------------
// xg = h_l0 @ W_ih1^T  (262144 x 256 x 128, split-bf16 3-combo, f32 out).
// 16384 blocks x 1024 threads; wave = one n-tile (16 gates), W frags in regs,
// block covers a 16-row M-tile. HBM-streaming bound (~400 MB).
// ---------------------------------------------------------------------------
__launch_bounds__(1024, 2)
__global__ void xg_gemm(const short* __restrict__ h,
                        const float* __restrict__ w1,
                        float* __restrict__ xg) {
    const int tid = threadIdx.x;
    const int nt  = tid >> 6;
    const int l   = tid & 63;
    const int col = l & 15;
    const int rg  = l >> 4;
    const size_t m0 = (size_t)blockIdx.x * 16;

    bf16x8 wh[4], wl[4];
    const int gate = nt * 16 + col;
#pragma unroll
    for (int ks = 0; ks < 4; ++ks) {
        const float* src = w1 + gate * DD1 + ks * 32 + 8 * rg;
#pragma unroll
        for (int e = 0; e < 8; ++e) {
            float v = src[e];
            short h16 = f2bf_rne(v);
            wh[ks][e] = h16;
            wl[ks][e] = f2bf_rne(v - bf2f(h16));
        }
    }

    const short* ap = h + (m0 + col) * GG + 8 * rg;
    bf16x8 ah[4], al[4];
#pragma unroll
    for (int ks = 0; ks < 4; ++ks) {
        ah[ks] = *(const bf16x8*)&ap[ks * 32];        // h_hi
        al[ks] = *(const bf16x8*)&ap[128 + ks * 32];  // h_lo
    }
    f32x4 a = {0.f, 0.f, 0.f, 0.f};
#pragma unroll
    for (int ks = 0; ks < 4; ++ks) {
        a = MFMA16(ah[ks], wh[ks], a);
        a = MFMA16(al[ks], wh[ks], a);
        a = MFMA16(ah[ks], wl[ks], a);
    }
#pragma unroll
    for (int j = 0; j < 4; ++j)
        xg[(m0 + rg * 4 + j) * GG + nt * 16 + col] = a[j];
}

// ---------------------------------------------------------------------------
// Layer 1 forward, LEAN recurrence: gates = xg[b][t] + h @ W_hh^T + bias.
// 512 blocks (2 rows each) -> 2 blocks/CU; 24 MFMA/wave/step; xg streamed
// from global with one-step LDS double-buffer. Only final h stored.
// ---------------------------------------------------------------------------
__launch_bounds__(256, 2)
__global__ void lstm_l1_lean(const float* __restrict__ xg,
                             const float* __restrict__ w_hh,
                             const float* __restrict__ b_ih, const float* __restrict__ b_hh,
                             float* __restrict__ h_last) {
    const int tid  = threadIdx.x;
    const int w    = tid >> 6;
    const int l    = tid & 63;
    const int col  = l & 15;
    const int rg   = l >> 4;
    const int row0 = blockIdx.x * 2;
    const int u    = w * 16 + col;

    __shared__ __align__(16) short hsf[2][2048];     // 8 KB
    __shared__ __align__(16) float xgs[2][2 * GG];   // 4 KB double buffer

    for (int i = tid; i < 2 * 2048; i += 256) ((short*)hsf)[i] = 0;

    bf16x8 whh_hi[4][2], whh_lo[4][2];
#pragma unroll
    for (int q = 0; q < 4; ++q) {
        const int gate = (w + 4 * q) * 16 + col;
#pragma unroll
        for (int ks = 0; ks < 2; ++ks) {
            const float* src = w_hh + gate * HH + ks * 32 + 8 * rg;
#pragma unroll
            for (int e = 0; e < 8; ++e) {
                float v = src[e];
                short h16 = f2bf_rne(v);
                whh_hi[q][ks][e] = h16;
                whh_lo[q][ks][e] = f2bf_rne(v - bf2f(h16));
            }
        }
    }
    float bb[4];
#pragma unroll
    for (int gi = 0; gi < 4; ++gi) bb[gi] = b_ih[u + 64 * gi] + b_hh[u + 64 * gi];

    const int prow = tid >> 7, pj = tid & 127;  // xg prefetch assignment
    {   // preload t = 0
        const float2 v = *(const float2*)&xg[(((size_t)(row0 + prow)) * TT + 0) * GG + pj * 2];
        *(float2*)&xgs[0][prow * GG + pj * 2] = v;
    }
    float cc[2] = {0.f, 0.f};
    __syncthreads();

    for (int t = 0; t < TT; ++t) {
        const int cur = t & 1, nxt = cur ^ 1;
        float2 pf;
        if (t + 1 < TT)
            pf = *(const float2*)&xg[(((size_t)(row0 + prow)) * TT + (t + 1)) * GG + pj * 2];

        const short* hb = &hsf[cur][0];
        bf16x8 ah0 = *(const bf16x8*)&hb[0 * 512 + l * 8];
        bf16x8 ah1 = *(const bf16x8*)&hb[1 * 512 + l * 8];
        bf16x8 ah2 = *(const bf16x8*)&hb[2 * 512 + l * 8];
        bf16x8 ah3 = *(const bf16x8*)&hb[3 * 512 + l * 8];
        f32x4 acc[4];
#pragma unroll
        for (int q = 0; q < 4; ++q) {
            f32x4 a = {0.f, 0.f, 0.f, 0.f};
            a = MFMA16(ah0, whh_hi[q][0], a);
            a = MFMA16(ah1, whh_hi[q][1], a);
            a = MFMA16(ah2, whh_hi[q][0], a);
            a = MFMA16(ah3, whh_hi[q][1], a);
            a = MFMA16(ah0, whh_lo[q][0], a);
            a = MFMA16(ah1, whh_lo[q][1], a);
            acc[q] = a;
        }
        if (rg == 0) {
#pragma unroll
            for (int r = 0; r < 2; ++r) {
                float g4[4];
#pragma unroll
                for (int gi = 0; gi < 4; ++gi)
                    g4[gi] = acc[gi][r] + xgs[cur][r * GG + u + 64 * gi] + bb[gi];
                const float cn = sigf(g4[1]) * cc[r] + sigf(g4[0]) * tanh_fast(g4[2]);
                const float hn = sigf(g4[3]) * tanh_fast(cn);
                cc[r] = cn;
                const short hi16 = f2bf_rne(hn);
                const int wa = hsf_waddr(u, r);
                hsf[nxt][wa]        = hi16;
                hsf[nxt][wa + 1024] = f2bf_rne(hn - bf2f(hi16));
                if (t == TT - 1) h_last[(size_t)(row0 + r) * HH + u] = hn;
            }
        }
        if (t + 1 < TT) *(float2*)&xgs[nxt][prow * GG + pj * 2] = pf;
        __syncthreads();
    }
}

// ---------------------------------------------------------------------------
// Layer 1 forward, FUSED (round-4, known-good) — fallback when ws is small.
// ---------------------------------------------------------------------------
__launch_bounds__(256, 1)
__global__ void lstm_l1_fused(const short* __restrict__ in0,
                              const float* __restrict__ w_ih, const float* __restrict__ w_hh,
                              const float* __restrict__ b_ih, const float* __restrict__ b_hh,
                              float* __restrict__ h_last) {
    const int tid  = threadIdx.x;
    const int w    = tid >> 6;
    const int l    = tid & 63;
    const int col  = l & 15;
    const int rg   = l >> 4;
    const int row0 = blockIdx.x * 8;
    const int u    = w * 16 + col;

    __shared__ __align__(16) short sh_wf[128][64 * 8];
    __shared__ __align__(16) short hs[2][16][136];

    for (int i = tid; i < 2 * 16 * 136; i += 256) ((short*)hs)[i] = 0;

    for (int it = 0; it < 16; ++it) {
        const int fih = w * 16 + it;
        const int nt = fih >> 2, ks = fih & 3;
        const float* src = w_ih + (nt * 16 + col) * DD1 + ks * 32 + 8 * rg;
        bf16x8 hi, lo;
#pragma unroll
        for (int e = 0; e < 8; ++e) {
            float v = src[e];
            short h16 = f2bf_rne(v);
            hi[e] = h16;
            lo[e] = f2bf_rne(v - bf2f(h16));
        }
        *(bf16x8*)&sh_wf[nt * 8 + ks][l * 8]     = hi;
        *(bf16x8*)&sh_wf[nt * 8 + 4 + ks][l * 8] = lo;
    }

    bf16x8 whh_hi[4][2], whh_lo[4][2];
#pragma unroll
    for (int q = 0; q < 4; ++q) {
        const int gate = (w + 4 * q) * 16 + col;
#pragma unroll
        for (int ks = 0; ks < 2; ++ks) {
            const float* src = w_hh + gate * HH + ks * 32 + 8 * rg;
#pragma unroll
            for (int e = 0; e < 8; ++e) {
                float v = src[e];
                short h16 = f2bf_rne(v);
                whh_hi[q][ks][e] = h16;
                whh_lo[q][ks][e] = f2bf_rne(v - bf2f(h16));
            }
        }
    }
    float bb[4];
#pragma unroll
    for (int gi = 0; gi < 4; ++gi) bb[gi] = b_ih[u + 64 * gi] + b_hh[u + 64 * gi];

    const int arow = row0 + (col < 8 ? col : 7);
    const short* xsrc = in0 + (size_t)arow * TT * 256 + 8 * rg;

    f32x4 c = {0.f, 0.f, 0.f, 0.f};
    bf16x8 xA[8], xB[8];

    auto loadx = [&](int t, bf16x8 (&xr)[8]) {
        const short* p = xsrc + (size_t)t * 256;
#pragma unroll
        for (int ks = 0; ks < 4; ++ks) {
            xr[ks]     = *(const bf16x8*)&p[ks * 32];
            xr[4 + ks] = *(const bf16x8*)&p[128 + ks * 32];
        }
    };

    auto step = [&](int t, const bf16x8 (&xr)[8]) {
        const int cur = t & 1;
        const short* hrow = &hs[cur][col][0];
        bf16x8 ah0 = *(const bf16x8*)&hrow[ 0 + 8 * rg];
        bf16x8 ah1 = *(const bf16x8*)&hrow[32 + 8 * rg];
        bf16x8 ah2 = *(const bf16x8*)&hrow[64 + 8 * rg];
        bf16x8 ah3 = *(const bf16x8*)&hrow[96 + 8 * rg];
        f32x4 acc[4];
#pragma unroll
        for (int q = 0; q < 4; ++q) {
            const int nt = w + 4 * q;
            f32x4 a = {0.f, 0.f, 0.f, 0.f};
            a = MFMA16(ah0, whh_hi[q][0], a);
            a = MFMA16(ah1, whh_hi[q][1], a);
            a = MFMA16(ah2, whh_hi[q][0], a);
            a = MFMA16(ah3, whh_hi[q][1], a);
            a = MFMA16(ah0, whh_lo[q][0], a);
            a = MFMA16(ah1, whh_lo[q][1], a);
#pragma unroll
            for (int ks = 0; ks < 4; ++ks) {
                bf16x8 wh = *(const bf16x8*)&sh_wf[nt * 8 + ks][l * 8];
                bf16x8 wl = *(const bf16x8*)&sh_wf[nt * 8 + 4 + ks][l * 8];
                a = MFMA16(xr[ks], wh, a);
                a = MFMA16(xr[4 + ks], wh, a);
                a = MFMA16(xr[ks], wl, a);
            }
            acc[q] = a;
        }
        if (rg < 2) {
            const int nxt = cur ^ 1;
#pragma unroll
            for (int r = 0; r < 4; ++r) {
                const int row = rg * 4 + r;
                const float gi_ = acc[0][r] + bb[0];
                const float gf_ = acc[1][r] + bb[1];
                const float gg_ = acc[2][r] + bb[2];
                const float go_ = acc[3][r] + bb[3];
                const float cn = sigf(gf_) * c[r] + sigf(gi_) * tanh_fast(gg_);
                const float hn = sigf(go_) * tanh_fast(cn);
                c[r] = cn;
                const short hi16 = f2bf_rne(hn);
                hs[nxt][row][u]      = hi16;
                hs[nxt][row][64 + u] = f2bf_rne(hn - bf2f(hi16));
                if (t == TT - 1) h_last[(size_t)(row0 + row) * HH + u] = hn;
            }
        }
        __syncthreads();
    };

    loadx(0, xA);
    __syncthreads();
    for (int t = 0; t < TT; t += 2) {
        loadx(t + 1, xB);
        step(t, xA);
        if (t + 2 < TT) loadx(t + 2, xA);
        step(t + 1, xB);
    }
}

// ---------------------------------------------------------------------------
// Tail: layer-1 backward is ONE step at t=T-1 from zero state (h0=0 kills the
// w_hh term), then FC. 1024 blocks, 256 threads.
// ---------------------------------------------------------------------------
__global__ void lstm_tail(const short* __restrict__ in0,
                          const float* __restrict__ h1f,
                          const float* __restrict__ w_ih_r,
                          const float* __restrict__ b_ih_r, const float* __restrict__ b_hh_r,
                          const float* __restrict__ fc_w, const float* __restrict__ fc_b,
                          float* __restrict__ out) {
    const int b   = blockIdx.x;
    const int tid = threadIdx.x;
    __shared__ __align__(16) float insl[DD1];
    __shared__ __align__(16) float hb[HH];
    __shared__ __align__(16) float gsh[256];

    if (tid < DD1) {
        const size_t base = ((size_t)b * TT + (TT - 1)) * 256;
        insl[tid] = bf2f(in0[base + tid]) + bf2f(in0[base + 128 + tid]);
    }
    __syncthreads();

    float a0 = b_ih_r[tid] + b_hh_r[tid], a1 = 0.f, a2 = 0.f, a3 = 0.f;
    const float4* in4 = (const float4*)insl;
#pragma unroll
    for (int kk = 0; kk < 32; ++kk) {
        float4 iv = in4[kk];
        float4 wv = *(const float4*)&w_ih_r[tid * DD1 + 4 * kk];
        a0 += wv.x * iv.x;
        a1 += wv.y * iv.y;
        a2 += wv.z * iv.z;
        a3 += wv.w * iv.w;
    }
    gsh[tid] = (a0 + a1) + (a2 + a3);
    __syncthreads();

    if (tid < HH) {
        const float gi = gsh[tid], gc = gsh[tid + 128], go = gsh[tid + 192];
        const float ccv = sigf(gi) * tanh_fast(gc);  // c_prev = 0
        hb[tid] = sigf(go) * tanh_fast(ccv);
    }
    __syncthreads();

    if (tid < 64) {
        float p = fc_w[tid] * h1f[(size_t)b * HH + tid] + fc_w[HH + tid] * hb[tid];
#pragma unroll
        for (int off = 32; off; off >>= 1) p += __shfl_xor(p, off);
        if (tid == 0) out[b] = p + fc_b[0];
    }
}

// ---------------------------------------------------------------------------
extern "C" void kernel_launch(void* const* d_in, const int* in_sizes, int n_in,
                              void* d_out, int out_size, void* d_ws, size_t ws_size,
                              hipStream_t stream) {
    const float* x = (const float*)d_in[0];
    // l0 fwd: 1..4, l0 rev: 5..8, l1 fwd: 9..12, l1 rev: 13..16, fc: 17,18
    char* ws = (char*)d_ws;
    const size_t out0_b = (size_t)NB * TT * GG * 2;   // 134.2 MB (h hi|lo bf16)
    const size_t xg_b   = (size_t)NB * TT * GG * 4;   // 268.4 MB (xg f32)
    const size_t h1f_b  = (size_t)NB * HH * 4;

    short* out0 = (short*)ws;

    lstm_l0<<<1024, 256, 0, stream>>>(
        x, (const float*)d_in[1], (const float*)d_in[2], (const float*)d_in[3], (const float*)d_in[4],
        (const float*)d_in[5], (const float*)d_in[6], (const float*)d_in[7], (const float*)d_in[8], out0);

    if (ws_size >= out0_b + xg_b + h1f_b) {
        float* xg  = (float*)(ws + out0_b);
        float* h1f = (float*)(ws + out0_b + xg_b);
        xg_gemm<<<NB * TT / 16, 1024, 0, stream>>>(out0, (const float*)d_in[9], xg);
        lstm_l1_lean<<<512, 256, 0, stream>>>(
            xg, (const float*)d_in[10], (const float*)d_in[11], (const float*)d_in[12], h1f);
        lstm_tail<<<1024, 256, 0, stream>>>(
            out0, h1f, (const float*)d_in[13], (const float*)d_in[15], (const float*)d_in[16],
            (const float*)d_in[17], (const float*)d_in[18], (float*)d_out);
    } else {
        float* h1f = (float*)(ws + out0_b);
        lstm_l1_fused<<<128, 256, 0, stream>>>(
            out0, (const float*)d_in[9], (const float*)d_in[10], (const float*)d_in[11],
            (const float*)d_in[12], h1f);
        lstm_tail<<<1024, 256, 0, stream>>>(
            out0, h1f, (const float*)d_in[13], (const float*)d_in[15], (const float*)d_in[16],
            (const float*)d_in[17], (const float*)d_in[18], (float*)d_out);
    }
}

// Round 6
// 1127.694 us; speedup vs baseline: 1.0011x; 1.0011x over previous
//
#include <hip/hip_runtime.h>
#include <hip/hip_bf16.h>

#define HH 64      // hidden
#define TT 256     // seq len
#define NB 1024    // batch
#define GG 256     // 4*H gates
#define DD0 5      // layer-0 input dim
#define DD1 128    // layer-1 input dim (2*H)

typedef __attribute__((ext_vector_type(8))) short bf16x8;  // 8 bf16 = 4 VGPR
typedef __attribute__((ext_vector_type(4))) float f32x4;   // MFMA C/D frag

#define MFMA16(a, b, c) __builtin_amdgcn_mfma_f32_16x16x32_bf16((a), (b), (c), 0, 0, 0)

__device__ __forceinline__ float sigf(float x) { return 1.0f / (1.0f + __expf(-x)); }
__device__ __forceinline__ float tanh_fast(float x) { return 2.0f / (1.0f + __expf(-2.0f * x)) - 1.0f; }

__device__ __forceinline__ float bf2f(short s) {
    unsigned int u = ((unsigned int)(unsigned short)s) << 16;
    return __builtin_bit_cast(float, u);
}
__device__ __forceinline__ short f2bf_rne(float x) {
    unsigned int u = __builtin_bit_cast(unsigned int, x);
    u += 0x7fffu + ((u >> 16) & 1u);  // round-to-nearest-even
    return (short)(u >> 16);
}

// Lane-linear A-fragment store for h (conflict-free ds_read_b128):
// reader lane l, seg s reads shorts [s*512 + l*8, +8) == h[row=l&15][k=s*32+8*(l>>4)+e].
__device__ __forceinline__ int hsf_waddr(int u, int row) {
    return ((u >> 5) * 512) + (((u >> 3) & 3) * 128) + row * 8 + (u & 7);  // lo plane: +1024
}

// out0 layout: u32[b][t][128 units] = bf16 hi (low16) | bf16 lo (high16).
// unit 0..63 = fwd, 64..127 = bwd.

// ---------------------------------------------------------------------------
// Layer 0, MFMA recurrence. 512 blocks = 256 row-quads x 2 dirs.
// 256 threads = 4 waves; wave w owns n-tile quad {w,w+4,w+8,w+12} so lane
// (rg==0, col) holds i,f,g,o of unit u = 16w+col for rows 0..3 (C/D reg r).
// h = split-bf16 (hi+lo) 3-combo MFMA; x-part (D=5) exact fp32 VALU.
// launch_bounds(256,2): VGPR cap 256 so whh frags STAY RESIDENT (round-5
// lesson: (256,4) capped at 128 -> rematerialized weights every step).
// ---------------------------------------------------------------------------
__launch_bounds__(256, 2)
__global__ void lstm_l0(const float* __restrict__ x,
                        const float* __restrict__ w_ih_f, const float* __restrict__ w_hh_f,
                        const float* __restrict__ b_ih_f, const float* __restrict__ b_hh_f,
                        const float* __restrict__ w_ih_r, const float* __restrict__ w_hh_r,
                        const float* __restrict__ b_ih_r, const float* __restrict__ b_hh_r,
                        unsigned int* __restrict__ out0) {
    const int tid  = threadIdx.x;
    const int w    = tid >> 6;
    const int l    = tid & 63;
    const int col  = l & 15;
    const int rg   = l >> 4;
    const int dir  = blockIdx.x & 1;
    const int row0 = (blockIdx.x >> 1) * 4;
    const int u    = w * 16 + col;

    const float* w_ih = dir ? w_ih_r : w_ih_f;
    const float* w_hh = dir ? w_hh_r : w_hh_f;
    const float* b_ih = dir ? b_ih_r : b_ih_f;
    const float* b_hh = dir ? b_hh_r : b_hh_f;

    __shared__ __align__(16) float xs[4 * TT * DD0];  // 20 KB
    __shared__ __align__(16) short hsf[2][2048];      // 8 KB

    {   // stage x: 4 rows x 1280 contiguous floats
        const float4* src = (const float4*)(x + (size_t)row0 * TT * DD0);
        for (int i = tid; i < 4 * TT * DD0 / 4; i += 256) ((float4*)xs)[i] = src[i];
    }
    for (int i = tid; i < 2 * 2048; i += 256) ((short*)hsf)[i] = 0;

    bf16x8 whh_hi[4][2], whh_lo[4][2];
#pragma unroll
    for (int q = 0; q < 4; ++q) {
        const int gate = (w + 4 * q) * 16 + col;
#pragma unroll
        for (int ks = 0; ks < 2; ++ks) {
            const float* src = w_hh + gate * HH + ks * 32 + 8 * rg;
#pragma unroll
            for (int e = 0; e < 8; ++e) {
                float v = src[e];
                short h16 = f2bf_rne(v);
                whh_hi[q][ks][e] = h16;
                whh_lo[q][ks][e] = f2bf_rne(v - bf2f(h16));
            }
        }
    }
    float wxi[4][DD0], bb[4];
#pragma unroll
    for (int gi = 0; gi < 4; ++gi) {
        const int gate = u + 64 * gi;
#pragma unroll
        for (int d = 0; d < DD0; ++d) wxi[gi][d] = w_ih[gate * DD0 + d];
        bb[gi] = b_ih[gate] + b_hh[gate];
    }

    f32x4 cc = {0.f, 0.f, 0.f, 0.f};
    __syncthreads();

    for (int t = 0; t < TT; ++t) {
        const int tt  = dir ? (TT - 1 - t) : t;
        const int cur = t & 1, nxt = cur ^ 1;
        const short* hb = &hsf[cur][0];
        bf16x8 ah0 = *(const bf16x8*)&hb[0 * 512 + l * 8];  // h_hi k 0..31
        bf16x8 ah1 = *(const bf16x8*)&hb[1 * 512 + l * 8];  // h_hi k 32..63
        bf16x8 ah2 = *(const bf16x8*)&hb[2 * 512 + l * 8];  // h_lo k 0..31
        bf16x8 ah3 = *(const bf16x8*)&hb[3 * 512 + l * 8];  // h_lo k 32..63
        // x values for this step (issued before MFMAs so latency hides)
        float xv[4][DD0];
#pragma unroll
        for (int r = 0; r < 4; ++r) {
            const float* xr = &xs[r * TT * DD0 + tt * DD0];
#pragma unroll
            for (int d = 0; d < DD0; ++d) xv[r][d] = xr[d];
        }
        f32x4 acc[4];
#pragma unroll
        for (int q = 0; q < 4; ++q) {
            f32x4 a = {0.f, 0.f, 0.f, 0.f};
            a = MFMA16(ah0, whh_hi[q][0], a);
            a = MFMA16(ah1, whh_hi[q][1], a);
            a = MFMA16(ah2, whh_hi[q][0], a);   // h_lo * w_hi
            a = MFMA16(ah3, whh_hi[q][1], a);
            a = MFMA16(ah0, whh_lo[q][0], a);   // h_hi * w_lo
            a = MFMA16(ah1, whh_lo[q][1], a);
            acc[q] = a;
        }
        if (rg == 0) {
#pragma unroll
            for (int r = 0; r < 4; ++r) {
                float g4[4];
#pragma unroll
                for (int gi = 0; gi < 4; ++gi)
                    g4[gi] = acc[gi][r] + bb[gi]
                           + wxi[gi][0] * xv[r][0] + wxi[gi][1] * xv[r][1]
                           + wxi[gi][2] * xv[r][2] + wxi[gi][3] * xv[r][3]
                           + wxi[gi][4] * xv[r][4];
                const float cn = sigf(g4[1]) * cc[r] + sigf(g4[0]) * tanh_fast(g4[2]);
                const float hn = sigf(g4[3]) * tanh_fast(cn);
                cc[r] = cn;
                const short hi16 = f2bf_rne(hn);
                const short lo16 = f2bf_rne(hn - bf2f(hi16));
                const int wa = hsf_waddr(u, r);
                hsf[nxt][wa]        = hi16;
                hsf[nxt][wa + 1024] = lo16;
                out0[((size_t)(row0 + r) * TT + tt) * 128 + dir * 64 + u] =
                    (unsigned int)(unsigned short)hi16 | ((unsigned int)(unsigned short)lo16 << 16);
            }
        }
        __syncthreads();
    }
}

// ---------------------------------------------------------------------------
// xg = h_l0 @ W_ih1^T  (262144 x 256 x 128, split-bf16 3-combo, f32 out).
// 16384 blocks x 1024 threads; wave = one n-tile (16 gates), W frags in regs,
// block covers a 16-row M-tile. Unpacks interleaved hi|lo u32 h.
// ---------------------------------------------------------------------------
__launch_bounds__(1024, 2)
__global__ void xg_gemm(const unsigned int* __restrict__ h,
                        const float* __restrict__ w1,
                        float* __restrict__ xg) {
    const int tid = threadIdx.x;
    const int nt  = tid >> 6;
    const int l   = tid & 63;
    const int col = l & 15;
    const int rg  = l >> 4;
    const size_t m0 = (size_t)blockIdx.x * 16;

    bf16x8 wh[4], wl[4];
    const int gate = nt * 16 + col;
#pragma unroll
    for (int ks = 0; ks < 4; ++ks) {
        const float* src = w1 + gate * DD1 + ks * 32 + 8 * rg;
#pragma unroll
        for (int e = 0; e < 8; ++e) {
            float v = src[e];
            short h16 = f2bf_rne(v);
            wh[ks][e] = h16;
            wl[ks][e] = f2bf_rne(v - bf2f(h16));
        }
    }

    const unsigned int* ap = h + (m0 + col) * 128 + 8 * rg;
    bf16x8 ah[4], al[4];
#pragma unroll
    for (int ks = 0; ks < 4; ++ks) {
        const uint4 p0 = *(const uint4*)&ap[ks * 32];
        const uint4 p1 = *(const uint4*)&ap[ks * 32 + 4];
        const unsigned int pp[8] = {p0.x, p0.y, p0.z, p0.w, p1.x, p1.y, p1.z, p1.w};
#pragma unroll
        for (int e = 0; e < 8; ++e) {
            ah[ks][e] = (short)(pp[e] & 0xffffu);
            al[ks][e] = (short)(pp[e] >> 16);
        }
    }
    f32x4 a = {0.f, 0.f, 0.f, 0.f};
#pragma unroll
    for (int ks = 0; ks < 4; ++ks) {
        a = MFMA16(ah[ks], wh[ks], a);
        a = MFMA16(al[ks], wh[ks], a);
        a = MFMA16(ah[ks], wl[ks], a);
    }
#pragma unroll
    for (int j = 0; j < 4; ++j)
        xg[(m0 + rg * 4 + j) * GG + nt * 16 + col] = a[j];
}

// ---------------------------------------------------------------------------
// Layer 1 forward, LEAN recurrence: gates = xg[b][t] + h @ W_hh^T + bias.
// 512 blocks (2 rows each); 24 MFMA/wave/step; xg streamed from global with
// one-step LDS double-buffer. Only final h stored.
// ---------------------------------------------------------------------------
__launch_bounds__(256, 2)
__global__ void lstm_l1_lean(const float* __restrict__ xg,
                             const float* __restrict__ w_hh,
                             const float* __restrict__ b_ih, const float* __restrict__ b_hh,
                             float* __restrict__ h_last) {
    const int tid  = threadIdx.x;
    const int w    = tid >> 6;
    const int l    = tid & 63;
    const int col  = l & 15;
    const int rg   = l >> 4;
    const int row0 = blockIdx.x * 2;
    const int u    = w * 16 + col;

    __shared__ __align__(16) short hsf[2][2048];     // 8 KB
    __shared__ __align__(16) float xgs[2][2 * GG];   // 4 KB double buffer

    for (int i = tid; i < 2 * 2048; i += 256) ((short*)hsf)[i] = 0;

    bf16x8 whh_hi[4][2], whh_lo[4][2];
#pragma unroll
    for (int q = 0; q < 4; ++q) {
        const int gate = (w + 4 * q) * 16 + col;
#pragma unroll
        for (int ks = 0; ks < 2; ++ks) {
            const float* src = w_hh + gate * HH + ks * 32 + 8 * rg;
#pragma unroll
            for (int e = 0; e < 8; ++e) {
                float v = src[e];
                short h16 = f2bf_rne(v);
                whh_hi[q][ks][e] = h16;
                whh_lo[q][ks][e] = f2bf_rne(v - bf2f(h16));
            }
        }
    }
    float bb[4];
#pragma unroll
    for (int gi = 0; gi < 4; ++gi) bb[gi] = b_ih[u + 64 * gi] + b_hh[u + 64 * gi];

    const int prow = tid >> 7, pj = tid & 127;  // xg prefetch assignment
    {   // preload t = 0
        const float2 v = *(const float2*)&xg[(((size_t)(row0 + prow)) * TT + 0) * GG + pj * 2];
        *(float2*)&xgs[0][prow * GG + pj * 2] = v;
    }
    float cc[2] = {0.f, 0.f};
    __syncthreads();

    for (int t = 0; t < TT; ++t) {
        const int cur = t & 1, nxt = cur ^ 1;
        float2 pf;
        if (t + 1 < TT)
            pf = *(const float2*)&xg[(((size_t)(row0 + prow)) * TT + (t + 1)) * GG + pj * 2];

        const short* hb = &hsf[cur][0];
        bf16x8 ah0 = *(const bf16x8*)&hb[0 * 512 + l * 8];
        bf16x8 ah1 = *(const bf16x8*)&hb[1 * 512 + l * 8];
        bf16x8 ah2 = *(const bf16x8*)&hb[2 * 512 + l * 8];
        bf16x8 ah3 = *(const bf16x8*)&hb[3 * 512 + l * 8];
        f32x4 acc[4];
#pragma unroll
        for (int q = 0; q < 4; ++q) {
            f32x4 a = {0.f, 0.f, 0.f, 0.f};
            a = MFMA16(ah0, whh_hi[q][0], a);
            a = MFMA16(ah1, whh_hi[q][1], a);
            a = MFMA16(ah2, whh_hi[q][0], a);
            a = MFMA16(ah3, whh_hi[q][1], a);
            a = MFMA16(ah0, whh_lo[q][0], a);
            a = MFMA16(ah1, whh_lo[q][1], a);
            acc[q] = a;
        }
        if (rg == 0) {
#pragma unroll
            for (int r = 0; r < 2; ++r) {
                float g4[4];
#pragma unroll
                for (int gi = 0; gi < 4; ++gi)
                    g4[gi] = acc[gi][r] + xgs[cur][r * GG + u + 64 * gi] + bb[gi];
                const float cn = sigf(g4[1]) * cc[r] + sigf(g4[0]) * tanh_fast(g4[2]);
                const float hn = sigf(g4[3]) * tanh_fast(cn);
                cc[r] = cn;
                const short hi16 = f2bf_rne(hn);
                const int wa = hsf_waddr(u, r);
                hsf[nxt][wa]        = hi16;
                hsf[nxt][wa + 1024] = f2bf_rne(hn - bf2f(hi16));
                if (t == TT - 1) h_last[(size_t)(row0 + r) * HH + u] = hn;
            }
        }
        if (t + 1 < TT) *(float2*)&xgs[nxt][prow * GG + pj * 2] = pf;
        __syncthreads();
    }
}

// ---------------------------------------------------------------------------
// Layer 1 forward, FUSED fallback (only if ws too small for xg). Unpacks the
// interleaved u32 h inside the prefetch (off critical path).
// ---------------------------------------------------------------------------
__launch_bounds__(256, 1)
__global__ void lstm_l1_fused(const unsigned int* __restrict__ in0,
                              const float* __restrict__ w_ih, const float* __restrict__ w_hh,
                              const float* __restrict__ b_ih, const float* __restrict__ b_hh,
                              float* __restrict__ h_last) {
    const int tid  = threadIdx.x;
    const int w    = tid >> 6;
    const int l    = tid & 63;
    const int col  = l & 15;
    const int rg   = l >> 4;
    const int row0 = blockIdx.x * 8;
    const int u    = w * 16 + col;

    __shared__ __align__(16) short sh_wf[128][64 * 8];
    __shared__ __align__(16) short hs[2][16][136];

    for (int i = tid; i < 2 * 16 * 136; i += 256) ((short*)hs)[i] = 0;

    for (int it = 0; it < 16; ++it) {
        const int fih = w * 16 + it;
        const int nt = fih >> 2, ks = fih & 3;
        const float* src = w_ih + (nt * 16 + col) * DD1 + ks * 32 + 8 * rg;
        bf16x8 hi, lo;
#pragma unroll
        for (int e = 0; e < 8; ++e) {
            float v = src[e];
            short h16 = f2bf_rne(v);
            hi[e] = h16;
            lo[e] = f2bf_rne(v - bf2f(h16));
        }
        *(bf16x8*)&sh_wf[nt * 8 + ks][l * 8]     = hi;
        *(bf16x8*)&sh_wf[nt * 8 + 4 + ks][l * 8] = lo;
    }

    bf16x8 whh_hi[4][2], whh_lo[4][2];
#pragma unroll
    for (int q = 0; q < 4; ++q) {
        const int gate = (w + 4 * q) * 16 + col;
#pragma unroll
        for (int ks = 0; ks < 2; ++ks) {
            const float* src = w_hh + gate * HH + ks * 32 + 8 * rg;
#pragma unroll
            for (int e = 0; e < 8; ++e) {
                float v = src[e];
                short h16 = f2bf_rne(v);
                whh_hi[q][ks][e] = h16;
                whh_lo[q][ks][e] = f2bf_rne(v - bf2f(h16));
            }
        }
    }
    float bb[4];
#pragma unroll
    for (int gi = 0; gi < 4; ++gi) bb[gi] = b_ih[u + 64 * gi] + b_hh[u + 64 * gi];

    const int arow = row0 + (col < 8 ? col : 7);
    const unsigned int* xsrc = in0 + (size_t)arow * TT * 128 + 8 * rg;

    f32x4 c = {0.f, 0.f, 0.f, 0.f};
    bf16x8 xA[8], xB[8];

    auto loadx = [&](int t, bf16x8 (&xr)[8]) {
        const unsigned int* p = xsrc + (size_t)t * 128;
#pragma unroll
        for (int ks = 0; ks < 4; ++ks) {
            const uint4 p0 = *(const uint4*)&p[ks * 32];
            const uint4 p1 = *(const uint4*)&p[ks * 32 + 4];
            const unsigned int pp[8] = {p0.x, p0.y, p0.z, p0.w, p1.x, p1.y, p1.z, p1.w};
#pragma unroll
            for (int e = 0; e < 8; ++e) {
                xr[ks][e]     = (short)(pp[e] & 0xffffu);
                xr[4 + ks][e] = (short)(pp[e] >> 16);
            }
        }
    };

    auto step = [&](int t, const bf16x8 (&xr)[8]) {
        const int cur = t & 1;
        const short* hrow = &hs[cur][col][0];
        bf16x8 ah0 = *(const bf16x8*)&hrow[ 0 + 8 * rg];
        bf16x8 ah1 = *(const bf16x8*)&hrow[32 + 8 * rg];
        bf16x8 ah2 = *(const bf16x8*)&hrow[64 + 8 * rg];
        bf16x8 ah3 = *(const bf16x8*)&hrow[96 + 8 * rg];
        f32x4 acc[4];
#pragma unroll
        for (int q = 0; q < 4; ++q) {
            const int nt = w + 4 * q;
            f32x4 a = {0.f, 0.f, 0.f, 0.f};
            a = MFMA16(ah0, whh_hi[q][0], a);
            a = MFMA16(ah1, whh_hi[q][1], a);
            a = MFMA16(ah2, whh_hi[q][0], a);
            a = MFMA16(ah3, whh_hi[q][1], a);
            a = MFMA16(ah0, whh_lo[q][0], a);
            a = MFMA16(ah1, whh_lo[q][1], a);
#pragma unroll
            for (int ks = 0; ks < 4; ++ks) {
                bf16x8 wh = *(const bf16x8*)&sh_wf[nt * 8 + ks][l * 8];
                bf16x8 wl = *(const bf16x8*)&sh_wf[nt * 8 + 4 + ks][l * 8];
                a = MFMA16(xr[ks], wh, a);
                a = MFMA16(xr[4 + ks], wh, a);
                a = MFMA16(xr[ks], wl, a);
            }
            acc[q] = a;
        }
        if (rg < 2) {
            const int nxt = cur ^ 1;
#pragma unroll
            for (int r = 0; r < 4; ++r) {
                const int row = rg * 4 + r;
                const float gi_ = acc[0][r] + bb[0];
                const float gf_ = acc[1][r] + bb[1];
                const float gg_ = acc[2][r] + bb[2];
                const float go_ = acc[3][r] + bb[3];
                const float cn = sigf(gf_) * c[r] + sigf(gi_) * tanh_fast(gg_);
                const float hn = sigf(go_) * tanh_fast(cn);
                c[r] = cn;
                const short hi16 = f2bf_rne(hn);
                hs[nxt][row][u]      = hi16;
                hs[nxt][row][64 + u] = f2bf_rne(hn - bf2f(hi16));
                if (t == TT - 1) h_last[(size_t)(row0 + row) * HH + u] = hn;
            }
        }
        __syncthreads();
    };

    loadx(0, xA);
    __syncthreads();
    for (int t = 0; t < TT; t += 2) {
        loadx(t + 1, xB);
        step(t, xA);
        if (t + 2 < TT) loadx(t + 2, xA);
        step(t + 1, xB);
    }
}

// ---------------------------------------------------------------------------
// Tail: layer-1 backward is ONE step at t=T-1 from zero state (h0=0 kills the
// w_hh term), then FC. 1024 blocks, 256 threads.
// ---------------------------------------------------------------------------
__global__ void lstm_tail(const unsigned int* __restrict__ in0,
                          const float* __restrict__ h1f,
                          const float* __restrict__ w_ih_r,
                          const float* __restrict__ b_ih_r, const float* __restrict__ b_hh_r,
                          const float* __restrict__ fc_w, const float* __restrict__ fc_b,
                          float* __restrict__ out) {
    const int b   = blockIdx.x;
    const int tid = threadIdx.x;
    __shared__ __align__(16) float insl[DD1];
    __shared__ __align__(16) float hb[HH];
    __shared__ __align__(16) float gsh[256];

    if (tid < DD1) {
        const unsigned int v = in0[((size_t)b * TT + (TT - 1)) * 128 + tid];
        insl[tid] = bf2f((short)(v & 0xffffu)) + bf2f((short)(v >> 16));
    }
    __syncthreads();

    float a0 = b_ih_r[tid] + b_hh_r[tid], a1 = 0.f, a2 = 0.f, a3 = 0.f;
    const float4* in4 = (const float4*)insl;
#pragma unroll
    for (int kk = 0; kk < 32; ++kk) {
        float4 iv = in4[kk];
        float4 wv = *(const float4*)&w_ih_r[tid * DD1 + 4 * kk];
        a0 += wv.x * iv.x;
        a1 += wv.y * iv.y;
        a2 += wv.z * iv.z;
        a3 += wv.w * iv.w;
    }
    gsh[tid] = (a0 + a1) + (a2 + a3);
    __syncthreads();

    if (tid < HH) {
        const float gi = gsh[tid], gc = gsh[tid + 128], go = gsh[tid + 192];
        const float ccv = sigf(gi) * tanh_fast(gc);  // c_prev = 0
        hb[tid] = sigf(go) * tanh_fast(ccv);
    }
    __syncthreads();

    if (tid < 64) {
        float p = fc_w[tid] * h1f[(size_t)b * HH + tid] + fc_w[HH + tid] * hb[tid];
#pragma unroll
        for (int off = 32; off; off >>= 1) p += __shfl_xor(p, off);
        if (tid == 0) out[b] = p + fc_b[0];
    }
}

// ---------------------------------------------------------------------------
extern "C" void kernel_launch(void* const* d_in, const int* in_sizes, int n_in,
                              void* d_out, int out_size, void* d_ws, size_t ws_size,
                              hipStream_t stream) {
    const float* x = (const float*)d_in[0];
    // l0 fwd: 1..4, l0 rev: 5..8, l1 fwd: 9..12, l1 rev: 13..16, fc: 17,18
    char* ws = (char*)d_ws;
    const size_t out0_b = (size_t)NB * TT * 128 * 4;  // 134.2 MB (u32 hi|lo)
    const size_t xg_b   = (size_t)NB * TT * GG * 4;   // 268.4 MB (xg f32)
    const size_t h1f_b  = (size_t)NB * HH * 4;

    unsigned int* out0 = (unsigned int*)ws;

    lstm_l0<<<512, 256, 0, stream>>>(
        x, (const float*)d_in[1], (const float*)d_in[2], (const float*)d_in[3], (const float*)d_in[4],
        (const float*)d_in[5], (const float*)d_in[6], (const float*)d_in[7], (const float*)d_in[8], out0);

    if (ws_size >= out0_b + xg_b + h1f_b) {
        float* xg  = (float*)(ws + out0_b);
        float* h1f = (float*)(ws + out0_b + xg_b);
        xg_gemm<<<NB * TT / 16, 1024, 0, stream>>>(out0, (const float*)d_in[9], xg);
        lstm_l1_lean<<<512, 256, 0, stream>>>(
            xg, (const float*)d_in[10], (const float*)d_in[11], (const float*)d_in[12], h1f);
        lstm_tail<<<1024, 256, 0, stream>>>(
            out0, h1f, (const float*)d_in[13], (const float*)d_in[15], (const float*)d_in[16],
            (const float*)d_in[17], (const float*)d_in[18], (float*)d_out);
    } else {
        float* h1f = (float*)(ws + out0_b);
        lstm_l1_fused<<<128, 256, 0, stream>>>(
            out0, (const float*)d_in[9], (const float*)d_in[10], (const float*)d_in[11],
            (const float*)d_in[12], h1f);
        lstm_tail<<<1024, 256, 0, stream>>>(
            out0, h1f, (const float*)d_in[13], (const float*)d_in[15], (const float*)d_in[16],
            (const float*)d_in[17], (const float*)d_in[18], (float*)d_out);
    }
}